// Round 10
// baseline (75.939 us; speedup 1.0000x reference)
//
#include <hip/hip_runtime.h>
#include <stdint.h>

#define K_DIM 4096
#define N_DIM 11008
#define M_DIM 256

typedef uint32_t u32;
using frag_ab = __attribute__((ext_vector_type(8))) short;   // 8 bf16
using frag_cd = __attribute__((ext_vector_type(4))) float;   // 4 f32

__device__ __forceinline__ u32 f2bf_rn(float f) {
    u32 u = __builtin_bit_cast(u32, f);
    return (u + 0x7FFFu + ((u >> 16) & 1u)) >> 16;   // round-to-nearest-even
}
__device__ __forceinline__ float bf2f(u32 b) {
    return __builtin_bit_cast(float, b << 16);
}

// bf16(32+v) = 0x4200 | (v<<2).  For packed byte q = hi<<4|lo:
// q*0x4004 = q<<14 | q<<2 (no carries); mask -> {32+lo, 32+hi} bf16x2.
#define BFCVT(q) ((u32)((__mul24((int)(q), 0x4004) & 0x003C003C) | 0x42004200))

// Kernel 1: rowsum[m] = sum_k round_bf16(x[m][k])  (so the +32 trick's
// rank-1 correction cancels exactly).
__global__ __launch_bounds__(256) void rowsum_kernel(const float* __restrict__ x,
                                                     float* __restrict__ rowsum) {
    const int row = blockIdx.x;
    const int tid = threadIdx.x;
    const float* xr = x + (size_t)row * K_DIM;
    float s = 0.0f;
#pragma unroll
    for (int p = 0; p < 4; ++p) {
        int i = p * 1024 + tid * 4;
        float4 v = *reinterpret_cast<const float4*>(xr + i);
        s += bf2f(f2bf_rn(v.x)) + bf2f(f2bf_rn(v.y)) +
             bf2f(f2bf_rn(v.z)) + bf2f(f2bf_rn(v.w));
    }
#pragma unroll
    for (int off = 32; off > 0; off >>= 1) s += __shfl_down(s, off, 64);
    __shared__ float wsum[4];
    if ((tid & 63) == 0) wsum[tid >> 6] = s;
    __syncthreads();
    if (tid == 0) rowsum[row] = wsum[0] + wsum[1] + wsum[2] + wsum[3];
}

// Kernel 2: build A' = x rounded to bf16, in MFMA-fragment-major layout:
// uint4 index ((mq*128 + s)*4 + mf)*64 + c*16 + l4 holds
// A[m = mq*64+mf*16+l4][k = s*32 + c*8 .. +7].  One wave-instruction in the
// GEMM then loads a full fragment with a single coalesced dwordx4.
__global__ __launch_bounds__(256) void permute_kernel(const float* __restrict__ x,
                                                      uint4* __restrict__ abuf) {
    const int bx = blockIdx.x;
    const int mb = bx >> 4, kb = bx & 15;
    const int tid = threadIdx.x;
    const int g = tid >> 6, c = (tid >> 4) & 3, r = tid & 15;
    const int mq = mb >> 2, mf = mb & 3;
    const float* src0 = x + (size_t)(mb * 16 + r) * K_DIM;
#pragma unroll
    for (int h = 0; h < 2; ++h) {
        int s = kb * 8 + g + 4 * h;
        const float* sp = src0 + s * 32 + c * 8;
        float4 v0 = *reinterpret_cast<const float4*>(sp);
        float4 v1 = *reinterpret_cast<const float4*>(sp + 4);
        uint4 w;
        w.x = f2bf_rn(v0.x) | (f2bf_rn(v0.y) << 16);
        w.y = f2bf_rn(v0.z) | (f2bf_rn(v0.w) << 16);
        w.z = f2bf_rn(v1.x) | (f2bf_rn(v1.y) << 16);
        w.w = f2bf_rn(v1.z) | (f2bf_rn(v1.w) << 16);
        abuf[(size_t)(((mq * 128 + s) * 4 + mf) * 64 + c * 16 + r)] = w;
    }
}

// ---- GEMM: no LDS, no per-tile barriers.  Wave tile 64m x 16n x 4096k.
// Depth-4 register pipeline of asm-volatile global loads (A' dwordx4 from
// L2-resident buffer, packed-B dwords from HBM) with counted vmcnt(24).

// 8 loads per step: 4 A-fragments (mf via imm offset) + 4 B dwords (p).
#define ISSUE(AS, QS) {                                                      \
    asm volatile("global_load_dwordx4 %0, %4, %5 offset:0\n\t"               \
                 "global_load_dwordx4 %1, %4, %5 offset:1024\n\t"            \
                 "global_load_dwordx4 %2, %4, %5 offset:2048\n\t"            \
                 "global_load_dwordx4 %3, %4, %5 offset:3072"                \
                 : "=&v"(AS[0]), "=&v"(AS[1]), "=&v"(AS[2]), "=&v"(AS[3])    \
                 : "v"(va), "s"(ap));                                        \
    asm volatile("global_load_dword %0, %4, %8\n\t"                          \
                 "global_load_dword %1, %5, %8\n\t"                          \
                 "global_load_dword %2, %6, %8\n\t"                          \
                 "global_load_dword %3, %7, %8"                              \
                 : "=&v"(QS[0]), "=&v"(QS[1]), "=&v"(QS[2]), "=&v"(QS[3])    \
                 : "v"(vb[0]), "v"(vb[1]), "v"(vb[2]), "v"(vb[3]), "s"(bp)); \
    ap += 4096; bp += (size_t)16 * N_DIM * 4; }

// Consume one 32-k step: wait for its 8 loads, pin order (rule #18),
// unpack int4->bf16, 4 MFMAs.
#define STEP(AS, QS, W) {                                                    \
    asm volatile("s_waitcnt vmcnt(" #W ")" ::: "memory");                    \
    __builtin_amdgcn_sched_barrier(0);                                       \
    union { frag_ab f; u32 u[4]; } bb;                                       \
    bb.u[0] = BFCVT(QS[0]); bb.u[1] = BFCVT(QS[1]);                          \
    bb.u[2] = BFCVT(QS[2]); bb.u[3] = BFCVT(QS[3]);                          \
    acc[0] = __builtin_amdgcn_mfma_f32_16x16x32_bf16(AS[0], bb.f, acc[0], 0, 0, 0); \
    acc[1] = __builtin_amdgcn_mfma_f32_16x16x32_bf16(AS[1], bb.f, acc[1], 0, 0, 0); \
    acc[2] = __builtin_amdgcn_mfma_f32_16x16x32_bf16(AS[2], bb.f, acc[2], 0, 0, 0); \
    acc[3] = __builtin_amdgcn_mfma_f32_16x16x32_bf16(AS[3], bb.f, acc[3], 0, 0, 0); }

__global__ __launch_bounds__(256, 4) void gemm_kernel(const int* __restrict__ qw,
                                                      const float* __restrict__ scales,
                                                      const float* __restrict__ zeroes,
                                                      const uint4* __restrict__ abuf,
                                                      const float* __restrict__ rowsum,
                                                      float* __restrict__ out) {
    const int tid  = threadIdx.x;
    const int lane = tid & 63;
    const int wid  = tid >> 6;
    const int l4   = lane & 15;
    const int c    = lane >> 4;

    // XCD-bijective swizzle (688 = 8*86): the 4 mq-blocks of one n-tile are
    // consecutive wg -> same XCD -> qweight slice served from its L2.
    const int orig = blockIdx.x;
    const int wg   = (orig & 7) * 86 + (orig >> 3);
    const int nb   = wg >> 2;          // 0..171
    const int mq   = wg & 3;           // 0..3
    const int m0   = mq * 64;
    const int n0   = nb * 64 + wid * 16;   // wave's 16 output cols

    const char* ap = (const char*)abuf + (size_t)mq * 524288;   // A' mq slice
    const char* bp = (const char*)qw;
    u32 va = (u32)(lane * 16);
    u32 vb[4];
#pragma unroll
    for (int p = 0; p < 4; ++p)
        vb[p] = (u32)(((c * 4 + p) * N_DIM + n0 + l4) * 4);

    frag_cd acc[4];
#pragma unroll
    for (int i = 0; i < 4; ++i) acc[i] = (frag_cd){0.f, 0.f, 0.f, 0.f};

    frag_ab A0[4], A1[4], A2[4], A3[4];
    u32 Q0[4], Q1[4], Q2[4], Q3[4];

    // prologue: fill 4-deep pipeline (32 loads in flight)
    ISSUE(A0, Q0); ISSUE(A1, Q1); ISSUE(A2, Q2); ISSUE(A3, Q3);

    // main: 31 x 4 steps; consume oldest set, refill it 4 steps ahead.
    // s_barrier each iter bounds intra-block drift so the 4 waves' identical
    // A-addresses (and adjacent B half-lines) dedupe in L1.
    for (int i = 0; i < 31; ++i) {
        STEP(A0, Q0, 24); ISSUE(A0, Q0);
        STEP(A1, Q1, 24); ISSUE(A1, Q1);
        STEP(A2, Q2, 24); ISSUE(A2, Q2);
        STEP(A3, Q3, 24); ISSUE(A3, Q3);
        __builtin_amdgcn_s_barrier();
    }
    // tail: steps 124..127, drain 24 -> 16 -> 8 -> 0
    STEP(A0, Q0, 24);
    STEP(A1, Q1, 16);
    STEP(A2, Q2, 8);
    STEP(A3, Q3, 0);

    // epilogue: out = sc*acc - (32*sc + zero)*rowsum
    const float sc = scales[n0 + l4];
    const float zp = zeroes[n0 + l4] + 32.0f * sc;
#pragma unroll
    for (int mf = 0; mf < 4; ++mf) {
        const float4 rs = *reinterpret_cast<const float4*>(&rowsum[m0 + mf * 16 + c * 4]);
        float* op = out + (size_t)(m0 + mf * 16 + c * 4) * N_DIM + n0 + l4;
        op[0]                  = sc * acc[mf][0] - zp * rs.x;
        op[N_DIM]              = sc * acc[mf][1] - zp * rs.y;
        op[2 * (size_t)N_DIM]  = sc * acc[mf][2] - zp * rs.z;
        op[3 * (size_t)N_DIM]  = sc * acc[mf][3] - zp * rs.w;
    }
}

extern "C" void kernel_launch(void* const* d_in, const int* in_sizes, int n_in,
                              void* d_out, int out_size, void* d_ws, size_t ws_size,
                              hipStream_t stream) {
    const float* x      = (const float*)d_in[0];
    const int*   qw     = (const int*)d_in[1];
    const float* scales = (const float*)d_in[2];
    const float* zeroes = (const float*)d_in[3];
    float* out = (float*)d_out;

    uint4* abuf   = (uint4*)d_ws;                                  // 2 MB
    float* rowsum = (float*)((char*)d_ws + (size_t)2 * 1024 * 1024);

    rowsum_kernel<<<M_DIM, 256, 0, stream>>>(x, rowsum);
    permute_kernel<<<256, 256, 0, stream>>>(x, abuf);
    gemm_kernel<<<688, 256, 0, stream>>>(qw, scales, zeroes, abuf, rowsum, out);
}